// Round 8
// baseline (159.363 us; speedup 1.0000x reference)
//
#include <hip/hip_runtime.h>
#include <hip/hip_bf16.h>

#define Bn 4
#define Ln 4096
#define Dn 1024
#define Hn 16
#define KSEL 41

typedef __attribute__((ext_vector_type(8))) _Float16 f16x8;
typedef __attribute__((ext_vector_type(4))) float f32x4;

// ---------- f32 -> f16 bits (RNE via hardware cvt) ----------
__device__ __forceinline__ unsigned short f2h(float f) {
    union { _Float16 h; unsigned short u; } c;
    c.h = (_Float16)f;
    return c.u;
}

// ---------- async global->LDS, 16B per lane ----------
__device__ __forceinline__ void gl2lds16(const unsigned short* g, unsigned short* l) {
    __builtin_amdgcn_global_load_lds(
        (const __attribute__((address_space(1))) unsigned int*)(uintptr_t)g,
        (__attribute__((address_space(3))) unsigned int*)(uintptr_t)l,
        16, 0, 0);
}
__device__ __forceinline__ void gl2lds16f(const float* g, float* l) {
    __builtin_amdgcn_global_load_lds(
        (const __attribute__((address_space(1))) unsigned int*)(uintptr_t)g,
        (__attribute__((address_space(3))) unsigned int*)(uintptr_t)l,
        16, 0, 0);
}

// ---------------- column sums of q and k ----------------
// grid (256, 8): x = t-chunk (16 rows), y = tensor*4 + b. 2048 blocks -> 8/CU.
__global__ void colsum_part(const float* __restrict__ q, const float* __restrict__ k,
                            float* __restrict__ part) {
    int tb = blockIdx.y; int tensor = tb >> 2, b = tb & 3;
    const float4* src = (const float4*)((tensor ? k : q) + (size_t)b * Ln * Dn);
    int d4 = threadIdx.x;
    int t0 = blockIdx.x * 16;
    float sx = 0.f, sy = 0.f, sz = 0.f, sw = 0.f;
    #pragma unroll
    for (int i = 0; i < 16; ++i) {
        float4 v = src[(size_t)(t0 + i) * 256 + d4];
        sx += v.x; sy += v.y; sz += v.z; sw += v.w;
    }
    float4 o; o.x = sx; o.y = sy; o.z = sz; o.w = sw;
    ((float4*)part)[((size_t)tb * 256 + blockIdx.x) * 256 + d4] = o;
}

// grid (4, 8): reduce 256 chunks per (tb, d)
__global__ void colsum_fin(const float* __restrict__ part, float* __restrict__ sums) {
    int tb = blockIdx.y; int d = blockIdx.x * 256 + threadIdx.x;
    float s = 0.f;
    for (int i = 0; i < 256; ++i) s += part[((size_t)tb * 256 + i) * 1024 + d];
    sums[(size_t)tb * 1024 + d] = s;
}

// ---------------- SQ/SK = colsum @ W^T + L*bias ----------------
__global__ void proj_sums(const float* __restrict__ sums,
                          const float* __restrict__ Wq, const float* __restrict__ bq,
                          const float* __restrict__ Wk, const float* __restrict__ bk,
                          float* __restrict__ SQK) {
    int t = blockIdx.y;
    const float* W    = t ? Wk : Wq;
    const float* bias = t ? bk : bq;
    const float* sv   = sums + (size_t)t * 4 * 1024;
    __shared__ float s_sv[4 * 1024];
    for (int i = threadIdx.x; i < 4 * 1024; i += 256) s_sv[i] = sv[i];
    __syncthreads();
    int wave = threadIdx.x >> 6, lane = threadIdx.x & 63;
    for (int rr = 0; rr < 4; ++rr) {
        int j = blockIdx.x * 16 + rr * 4 + wave;
        float p[4] = {0.f, 0.f, 0.f, 0.f};
        for (int c = 0; c < 4; ++c) {
            float4 wv = *(const float4*)(W + (size_t)j * 1024 + c * 256 + lane * 4);
            #pragma unroll
            for (int b = 0; b < 4; ++b) {
                float4 s = *(const float4*)(s_sv + b * 1024 + c * 256 + lane * 4);
                p[b] += wv.x * s.x + wv.y * s.y + wv.z * s.z + wv.w * s.w;
            }
        }
        #pragma unroll
        for (int b = 0; b < 4; ++b)
            for (int off = 1; off < 64; off <<= 1) p[b] += __shfl_xor(p[b], off);
        if (lane == 0) {
            float bb = bias[j] * (float)Ln;
            #pragma unroll
            for (int b = 0; b < 4; ++b) SQK[((size_t)t * 4 + b) * 1024 + j] = p[b] + bb;
        }
    }
}

// ---------------- fused mean_value + top-41 + softmax + dense tap table ----------------
__global__ void stats_topk(const float* __restrict__ SQK, int* __restrict__ dly,
                           float* __restrict__ gp) {
    __shared__ float s_mv[4][64];
    __shared__ float mab[64];
    __shared__ float selv[4][KSEL];
    __shared__ int   s_dly[KSEL];
    int tid = threadIdx.x; int b = tid >> 6, c = tid & 63;
    const float* SQ = SQK; const float* SK = SQK + 4 * 1024;
    float s = 0.f;
    for (int h = 0; h < Hn; ++h)
        s += SQ[(size_t)b * 1024 + h * 64 + c] * SK[(size_t)b * 1024 + h * 64 + c];
    s_mv[b][c] = s * (1.0f / ((float)Hn * (float)Ln));
    __syncthreads();
    if (tid < 64) mab[c] = (s_mv[0][c] + s_mv[1][c] + s_mv[2][c] + s_mv[3][c]) * 0.25f;
    __syncthreads();
    if (tid < 64) {
        float my = mab[c];
        int rank = 0;
        for (int j = 0; j < 64; ++j) {
            float vj = mab[j];
            rank += (vj > my) || (vj == my && j < c);
        }
        if (rank < KSEL) {
            s_dly[rank] = c;
            dly[rank] = c;
            selv[0][rank] = s_mv[0][c]; selv[1][rank] = s_mv[1][c];
            selv[2][rank] = s_mv[2][c]; selv[3][rank] = s_mv[3][c];
        }
    }
    __syncthreads();
    if (tid < 256) gp[tid] = 0.f;
    __syncthreads();
    if (tid < 4) {
        float mx = -1e30f;
        for (int i = 0; i < KSEL; ++i) mx = fmaxf(mx, selv[tid][i]);
        float ss = 0.f;
        for (int i = 0; i < KSEL; ++i) ss += expf(selv[tid][i] - mx);
        float inv = 1.0f / ss;
        for (int i = 0; i < KSEL; ++i)
            gp[tid * 64 + s_dly[i]] = expf(selv[tid][i] - mx) * inv;
    }
}

// ---------------- weight prep: z=0 Wo->f16 straight; z=1 Wv->transpose->f16 ----------------
__global__ void prep_w(const float* __restrict__ Wo, const float* __restrict__ Wv,
                       unsigned short* __restrict__ Wof, unsigned short* __restrict__ WvTf) {
    int bx = blockIdx.x * 32, by = blockIdx.y * 32;
    int x = threadIdx.x, y0 = threadIdx.y;
    if (blockIdx.z == 0) {
        for (int i = 0; i < 32; i += 8) {
            size_t idx = (size_t)(by + y0 + i) * 1024 + bx + x;
            Wof[idx] = f2h(Wo[idx]);
        }
    } else {
        __shared__ float t[32][33];
        for (int i = 0; i < 32; i += 8)
            t[y0 + i][x] = Wv[(size_t)(by + y0 + i) * 1024 + bx + x];
        __syncthreads();
        for (int i = 0; i < 32; i += 8)
            WvTf[(size_t)(bx + y0 + i) * 1024 + by + x] = f2h(t[x][y0 + i]);
    }
}

// ---------------- bc = Wo @ bv + bo (fp32) ----------------
__global__ void bcvec_k(const float* __restrict__ Wo, const float* __restrict__ bv,
                        const float* __restrict__ bo, float* __restrict__ bc) {
    __shared__ float s_bv[1024];
    for (int i = threadIdx.x; i < 1024; i += 256) s_bv[i] = bv[i];
    __syncthreads();
    int wave = threadIdx.x >> 6, lane = threadIdx.x & 63;
    for (int rr = 0; rr < 4; ++rr) {
        int n = blockIdx.x * 16 + rr * 4 + wave;
        float p = 0.f;
        for (int c = 0; c < 4; ++c) {
            float4 wv = *(const float4*)(Wo + (size_t)n * 1024 + c * 256 + lane * 4);
            float4 s  = *(const float4*)(s_bv + c * 256 + lane * 4);
            p += wv.x * s.x + wv.y * s.y + wv.z * s.z + wv.w * s.w;
        }
        for (int off = 1; off < 64; off <<= 1) p += __shfl_xor(p, off);
        if (lane == 0) bc[n] = p + bo[n];
    }
}

// ---------------- gather as dense 64-tap FIR, 2 chunks of 32 taps -> f16 ----------------
#define FT 128
#define FC 64
#define FW 64
__global__ __launch_bounds__(256) void gather_fir(const float* __restrict__ v,
                                                  const float* __restrict__ gp,
                                                  unsigned short* __restrict__ Vf) {
    __shared__ float S[(FT + FW) * FC];   // 192 rows x 64 ch = 48 KB
    int b = blockIdx.z, c0 = blockIdx.y * FC, t0 = blockIdx.x * FT;
    const float* Vb = v + (size_t)b * Ln * Dn;
    #pragma unroll
    for (int it = 0; it < 12; ++it) {
        int idx = it * 256 + threadIdx.x;           // 16B slot
        int r = idx >> 4, cc = idx & 15;
        int gr = (t0 + r) & (Ln - 1);
        gl2lds16f(Vb + (size_t)gr * Dn + c0 + cc * 4, S + idx * 4);
    }
    __syncthreads();
    int c4 = threadIdx.x & 15, rg = threadIdx.x >> 4;   // 16 row-groups of 8 t
    const int base = rg * 8;
    float4 acc[8];
    #pragma unroll
    for (int i = 0; i < 8; ++i) acc[i] = make_float4(0.f, 0.f, 0.f, 0.f);
    #pragma unroll
    for (int tc = 0; tc < 2; ++tc) {
        float gc[32];
        #pragma unroll
        for (int j = 0; j < 8; ++j) {
            float4 gv = ((const float4*)(gp + b * 64 + tc * 32))[j];
            gc[j * 4 + 0] = gv.x; gc[j * 4 + 1] = gv.y;
            gc[j * 4 + 2] = gv.z; gc[j * 4 + 3] = gv.w;
        }
        #pragma unroll
        for (int w = 0; w < 39; ++w) {                  // 32 taps + 8 rows - 1
            float4 x = *(const float4*)&S[(base + tc * 32 + w) * FC + c4 * 4];
            #pragma unroll
            for (int i = 0; i < 8; ++i) {
                int j = w - i;                          // compile-time
                if (j >= 0 && j < 32) {
                    float wt = gc[j];
                    acc[i].x += wt * x.x; acc[i].y += wt * x.y;
                    acc[i].z += wt * x.z; acc[i].w += wt * x.w;
                }
            }
        }
    }
    #pragma unroll
    for (int i = 0; i < 8; ++i) {
        size_t idx = ((size_t)b * Ln + t0 + base + i) * Dn + c0 + c4 * 4;
        ushort4 o;
        o.x = f2h(acc[i].x); o.y = f2h(acc[i].y);
        o.z = f2h(acc[i].z); o.w = f2h(acc[i].w);
        *(ushort4*)&Vf[idx] = o;
    }
}

// ---------------- f16 single-MFMA NT GEMM (m97 structure) ----------------
template <int BM, bool OUT_F16>
__global__ __launch_bounds__(256, 2) void gemm_f16(
    const unsigned short* __restrict__ A, const unsigned short* __restrict__ Bt,
    float* __restrict__ C, unsigned short* __restrict__ Cf,
    const float* __restrict__ bias,
    int N, int K, int nbx) {
    constexpr int FM = BM / 32;
    __shared__ unsigned short sA[BM * 32];
    __shared__ unsigned short sB[BM * 32];

    int nwg = gridDim.x;
    int bid = blockIdx.x;
    int swz = (bid % 8) * (nwg / 8) + bid / 8;   // nwg % 8 == 0 for our grids
    int by = swz / nbx, bx = swz % nbx;

    const int wave = threadIdx.x >> 6, lane = threadIdx.x & 63;
    const int lrow = lane & 15, lk = (lane >> 4) * 8;
    const int wr = wave >> 1, wc = wave & 1;

    f32x4 acc[FM][FM];
    #pragma unroll
    for (int i = 0; i < FM; ++i)
        #pragma unroll
        for (int j = 0; j < FM; ++j) acc[i][j] = (f32x4){0.f, 0.f, 0.f, 0.f};

    const int srow = lane >> 2;
    const int skq  = (lane & 3) * 8;

    for (int k0 = 0; k0 < K; k0 += 32) {
        #pragma unroll
        for (int j = 0; j < BM / 64; ++j) {
            int chunk = j * 4 + wave;
            int row = chunk * 16 + srow;
            gl2lds16(A  + (size_t)((by * BM) + row) * K + k0 + skq, sA + chunk * 512);
            gl2lds16(Bt + (size_t)((bx * BM) + row) * K + k0 + skq, sB + chunk * 512);
        }
        __syncthreads();
        f16x8 bfrag[FM];
        #pragma unroll
        for (int j = 0; j < FM; ++j) {
            int r = wc * (BM / 2) + j * 16 + lrow;
            bfrag[j] = *(const f16x8*)&sB[r * 32 + lk];
        }
        #pragma unroll
        for (int i = 0; i < FM; ++i) {
            int r = wr * (BM / 2) + i * 16 + lrow;
            f16x8 afrag = *(const f16x8*)&sA[r * 32 + lk];
            #pragma unroll
            for (int j = 0; j < FM; ++j)
                acc[i][j] = __builtin_amdgcn_mfma_f32_16x16x32_f16(afrag, bfrag[j], acc[i][j], 0, 0, 0);
        }
        __syncthreads();
    }
    #pragma unroll
    for (int i = 0; i < FM; ++i) {
        int r0 = by * BM + wr * (BM / 2) + i * 16 + (lane >> 4) * 4;
        #pragma unroll
        for (int j = 0; j < FM; ++j) {
            int c = bx * BM + wc * (BM / 2) + j * 16 + (lane & 15);
            float bb = OUT_F16 ? 0.f : bias[c];
            #pragma unroll
            for (int r = 0; r < 4; ++r) {
                size_t idx = (size_t)(r0 + r) * N + c;
                if (OUT_F16) Cf[idx] = f2h(acc[i][j][r]);
                else         C[idx]  = acc[i][j][r] + bb;
            }
        }
    }
}

extern "C" void kernel_launch(void* const* d_in, const int* in_sizes, int n_in,
                              void* d_out, int out_size, void* d_ws, size_t ws_size,
                              hipStream_t stream) {
    const float* q  = (const float*)d_in[0];
    const float* k  = (const float*)d_in[1];
    const float* v  = (const float*)d_in[2];
    const float* Wq = (const float*)d_in[3];
    const float* bq = (const float*)d_in[4];
    const float* Wk = (const float*)d_in[5];
    const float* bk = (const float*)d_in[6];
    const float* Wv = (const float*)d_in[7];
    const float* bv = (const float*)d_in[8];
    const float* Wo = (const float*)d_in[9];
    const float* bo = (const float*)d_in[10];
    float* out = (float*)d_out;
    float* ws  = (float*)d_ws;

    unsigned short* Vf    = (unsigned short*)ws;        // 16777216 ushort (32 MB)
    unsigned short* Wof   = Vf + 16777216;              // 1048576
    unsigned short* WvTf  = Wof + 1048576;              // 1048576
    unsigned short* Wcf   = WvTf + 1048576;             // 1048576
    float* part = (float*)(Wcf + 1048576);              // 2097152 floats (8 MB)
    float* sums = part + 2097152;                       // 8192
    float* SQK  = sums + 8192;                          // 8192
    float* gp   = SQK + 8192;                           // 256 (4 x 64 dense taps)
    float* bc   = gp + 256;                             // 1024
    int*   dly  = (int*)(bc + 1024);                    // 64

    // correlation-stats chain -> dense tap table gp
    hipLaunchKernelGGL(colsum_part, dim3(256, 8), dim3(256), 0, stream, q, k, part);
    hipLaunchKernelGGL(colsum_fin, dim3(4, 8), dim3(256), 0, stream, part, sums);
    hipLaunchKernelGGL(proj_sums, dim3(64, 2), dim3(256), 0, stream, sums, Wq, bq, Wk, bk, SQK);
    hipLaunchKernelGGL(stats_topk, dim3(1), dim3(256), 0, stream, SQK, dly, gp);

    // weight prep: Wo->f16, WvT->f16; Wc = Wo @ Wv (f16 out); bc = Wo@bv + bo
    hipLaunchKernelGGL(prep_w, dim3(32, 32, 2), dim3(32, 8), 0, stream, Wo, Wv, Wof, WvTf);
    hipLaunchKernelGGL((gemm_f16<64, true>), dim3(256), dim3(256), 0, stream,
                       Wof, WvTf, (float*)nullptr, Wcf, (const float*)nullptr,
                       1024, 1024, 16);
    hipLaunchKernelGGL(bcvec_k, dim3(64), dim3(256), 0, stream, Wo, bv, bo, bc);

    // gather on v as dense 64-tap FIR (2x32-tap chunks) -> f16
    hipLaunchKernelGGL(gather_fir, dim3(32, 16, 4), dim3(256), 0, stream, v, gp, Vf);

    // out = Vagg @ Wc^T + bc  (16384 x 1024 x 1024), single f16 MFMA
    hipLaunchKernelGGL((gemm_f16<128, false>), dim3(1024), dim3(256), 0, stream,
                       Vf, Wcf, out, (unsigned short*)nullptr, bc, 1024, 1024, 8);
}

// Round 10
// 138.731 us; speedup vs baseline: 1.1487x; 1.1487x over previous
//
#include <hip/hip_runtime.h>
#include <hip/hip_bf16.h>

#define Bn 4
#define Ln 4096
#define Dn 1024
#define Hn 16
#define KSEL 41

typedef __attribute__((ext_vector_type(8))) _Float16 f16x8;
typedef __attribute__((ext_vector_type(4))) float f32x4;

// ---------- f32 -> f16 bits (RNE via hardware cvt) ----------
__device__ __forceinline__ unsigned short f2h(float f) {
    union { _Float16 h; unsigned short u; } c;
    c.h = (_Float16)f;
    return c.u;
}

// ---------- async global->LDS, 16B per lane ----------
__device__ __forceinline__ void gl2lds16(const unsigned short* g, unsigned short* l) {
    __builtin_amdgcn_global_load_lds(
        (const __attribute__((address_space(1))) unsigned int*)(uintptr_t)g,
        (__attribute__((address_space(3))) unsigned int*)(uintptr_t)l,
        16, 0, 0);
}
__device__ __forceinline__ void gl2lds16f(const float* g, float* l) {
    __builtin_amdgcn_global_load_lds(
        (const __attribute__((address_space(1))) unsigned int*)(uintptr_t)g,
        (__attribute__((address_space(3))) unsigned int*)(uintptr_t)l,
        16, 0, 0);
}

// ---------------- column sums of q and k ----------------
// grid (32, 8): x = t-chunk (128 rows), y = tensor*4 + b.
// 8 NAMED nontemporal 16B loads per burst => 8KB in flight per wave
// (round-8 lesson: occupancy 9.7->48% changed nothing; per-wave MLP is the lever).
__global__ __launch_bounds__(256) void colsum_part(const float* __restrict__ q,
                                                   const float* __restrict__ k,
                                                   float* __restrict__ part) {
    int tb = blockIdx.y; int tensor = tb >> 2, b = tb & 3;
    const f32x4* src = (const f32x4*)((tensor ? k : q) + (size_t)b * Ln * Dn) + threadIdx.x;
    int t0 = blockIdx.x * 128;
    f32x4 a0 = (f32x4){0.f, 0.f, 0.f, 0.f};
    f32x4 a1 = (f32x4){0.f, 0.f, 0.f, 0.f};
    #pragma unroll 1
    for (int g = 0; g < 16; ++g) {
        const f32x4* p = src + (size_t)(t0 + g * 8) * 256;
        f32x4 v0 = __builtin_nontemporal_load(p + 0 * 256);
        f32x4 v1 = __builtin_nontemporal_load(p + 1 * 256);
        f32x4 v2 = __builtin_nontemporal_load(p + 2 * 256);
        f32x4 v3 = __builtin_nontemporal_load(p + 3 * 256);
        f32x4 v4 = __builtin_nontemporal_load(p + 4 * 256);
        f32x4 v5 = __builtin_nontemporal_load(p + 5 * 256);
        f32x4 v6 = __builtin_nontemporal_load(p + 6 * 256);
        f32x4 v7 = __builtin_nontemporal_load(p + 7 * 256);
        a0 += v0 + v2 + v4 + v6;
        a1 += v1 + v3 + v5 + v7;
    }
    f32x4 o = a0 + a1;
    ((f32x4*)part)[((size_t)tb * 32 + blockIdx.x) * 256 + threadIdx.x] = o;
}

// grid (4, 8): reduce 32 chunks per (tb, d) — 1 MB total, trivial
__global__ void colsum_fin(const float* __restrict__ part, float* __restrict__ sums) {
    int tb = blockIdx.y; int d = blockIdx.x * 256 + threadIdx.x;
    float s = 0.f;
    for (int i = 0; i < 32; ++i) s += part[((size_t)tb * 32 + i) * 1024 + d];
    sums[(size_t)tb * 1024 + d] = s;
}

// ---------------- SQ/SK = colsum @ W^T + L*bias ----------------
__global__ void proj_sums(const float* __restrict__ sums,
                          const float* __restrict__ Wq, const float* __restrict__ bq,
                          const float* __restrict__ Wk, const float* __restrict__ bk,
                          float* __restrict__ SQK) {
    int t = blockIdx.y;
    const float* W    = t ? Wk : Wq;
    const float* bias = t ? bk : bq;
    const float* sv   = sums + (size_t)t * 4 * 1024;
    __shared__ float s_sv[4 * 1024];
    for (int i = threadIdx.x; i < 4 * 1024; i += 256) s_sv[i] = sv[i];
    __syncthreads();
    int wave = threadIdx.x >> 6, lane = threadIdx.x & 63;
    for (int rr = 0; rr < 4; ++rr) {
        int j = blockIdx.x * 16 + rr * 4 + wave;
        float p[4] = {0.f, 0.f, 0.f, 0.f};
        for (int c = 0; c < 4; ++c) {
            float4 wv = *(const float4*)(W + (size_t)j * 1024 + c * 256 + lane * 4);
            #pragma unroll
            for (int b = 0; b < 4; ++b) {
                float4 s = *(const float4*)(s_sv + b * 1024 + c * 256 + lane * 4);
                p[b] += wv.x * s.x + wv.y * s.y + wv.z * s.z + wv.w * s.w;
            }
        }
        #pragma unroll
        for (int b = 0; b < 4; ++b)
            for (int off = 1; off < 64; off <<= 1) p[b] += __shfl_xor(p[b], off);
        if (lane == 0) {
            float bb = bias[j] * (float)Ln;
            #pragma unroll
            for (int b = 0; b < 4; ++b) SQK[((size_t)t * 4 + b) * 1024 + j] = p[b] + bb;
        }
    }
}

// ---------------- fused mean_value + top-41 + softmax + dense tap table ----------------
__global__ void stats_topk(const float* __restrict__ SQK, int* __restrict__ dly,
                           float* __restrict__ gp) {
    __shared__ float s_mv[4][64];
    __shared__ float mab[64];
    __shared__ float selv[4][KSEL];
    __shared__ int   s_dly[KSEL];
    int tid = threadIdx.x; int b = tid >> 6, c = tid & 63;
    const float* SQ = SQK; const float* SK = SQK + 4 * 1024;
    float s = 0.f;
    for (int h = 0; h < Hn; ++h)
        s += SQ[(size_t)b * 1024 + h * 64 + c] * SK[(size_t)b * 1024 + h * 64 + c];
    s_mv[b][c] = s * (1.0f / ((float)Hn * (float)Ln));
    __syncthreads();
    if (tid < 64) mab[c] = (s_mv[0][c] + s_mv[1][c] + s_mv[2][c] + s_mv[3][c]) * 0.25f;
    __syncthreads();
    if (tid < 64) {
        float my = mab[c];
        int rank = 0;
        for (int j = 0; j < 64; ++j) {
            float vj = mab[j];
            rank += (vj > my) || (vj == my && j < c);
        }
        if (rank < KSEL) {
            s_dly[rank] = c;
            dly[rank] = c;
            selv[0][rank] = s_mv[0][c]; selv[1][rank] = s_mv[1][c];
            selv[2][rank] = s_mv[2][c]; selv[3][rank] = s_mv[3][c];
        }
    }
    __syncthreads();
    if (tid < 256) gp[tid] = 0.f;
    __syncthreads();
    if (tid < 4) {
        float mx = -1e30f;
        for (int i = 0; i < KSEL; ++i) mx = fmaxf(mx, selv[tid][i]);
        float ss = 0.f;
        for (int i = 0; i < KSEL; ++i) ss += expf(selv[tid][i] - mx);
        float inv = 1.0f / ss;
        for (int i = 0; i < KSEL; ++i)
            gp[tid * 64 + s_dly[i]] = expf(selv[tid][i] - mx) * inv;
    }
}

// ---------------- weight prep: z=0 Wo->f16 straight; z=1 Wv->transpose->f16 ----------------
__global__ void prep_w(const float* __restrict__ Wo, const float* __restrict__ Wv,
                       unsigned short* __restrict__ Wof, unsigned short* __restrict__ WvTf) {
    int bx = blockIdx.x * 32, by = blockIdx.y * 32;
    int x = threadIdx.x, y0 = threadIdx.y;
    if (blockIdx.z == 0) {
        for (int i = 0; i < 32; i += 8) {
            size_t idx = (size_t)(by + y0 + i) * 1024 + bx + x;
            Wof[idx] = f2h(Wo[idx]);
        }
    } else {
        __shared__ float t[32][33];
        for (int i = 0; i < 32; i += 8)
            t[y0 + i][x] = Wv[(size_t)(by + y0 + i) * 1024 + bx + x];
        __syncthreads();
        for (int i = 0; i < 32; i += 8)
            WvTf[(size_t)(bx + y0 + i) * 1024 + by + x] = f2h(t[x][y0 + i]);
    }
}

// ---------------- bc = Wo @ bv + bo (fp32) ----------------
__global__ void bcvec_k(const float* __restrict__ Wo, const float* __restrict__ bv,
                        const float* __restrict__ bo, float* __restrict__ bc) {
    __shared__ float s_bv[1024];
    for (int i = threadIdx.x; i < 1024; i += 256) s_bv[i] = bv[i];
    __syncthreads();
    int wave = threadIdx.x >> 6, lane = threadIdx.x & 63;
    for (int rr = 0; rr < 4; ++rr) {
        int n = blockIdx.x * 16 + rr * 4 + wave;
        float p = 0.f;
        for (int c = 0; c < 4; ++c) {
            float4 wv = *(const float4*)(Wo + (size_t)n * 1024 + c * 256 + lane * 4);
            float4 s  = *(const float4*)(s_bv + c * 256 + lane * 4);
            p += wv.x * s.x + wv.y * s.y + wv.z * s.z + wv.w * s.w;
        }
        for (int off = 1; off < 64; off <<= 1) p += __shfl_xor(p, off);
        if (lane == 0) bc[n] = p + bo[n];
    }
}

// ---------------- gather as dense 64-tap FIR, 2 chunks of 32 taps -> f16 ----------------
#define FT 128
#define FC 64
#define FW 64
__global__ __launch_bounds__(256) void gather_fir(const float* __restrict__ v,
                                                  const float* __restrict__ gp,
                                                  unsigned short* __restrict__ Vf) {
    __shared__ float S[(FT + FW) * FC];   // 192 rows x 64 ch = 48 KB
    int b = blockIdx.z, c0 = blockIdx.y * FC, t0 = blockIdx.x * FT;
    const float* Vb = v + (size_t)b * Ln * Dn;
    #pragma unroll
    for (int it = 0; it < 12; ++it) {
        int idx = it * 256 + threadIdx.x;           // 16B slot
        int r = idx >> 4, cc = idx & 15;
        int gr = (t0 + r) & (Ln - 1);
        gl2lds16f(Vb + (size_t)gr * Dn + c0 + cc * 4, S + idx * 4);
    }
    __syncthreads();
    int c4 = threadIdx.x & 15, rg = threadIdx.x >> 4;   // 16 row-groups of 8 t
    const int base = rg * 8;
    float4 acc[8];
    #pragma unroll
    for (int i = 0; i < 8; ++i) acc[i] = make_float4(0.f, 0.f, 0.f, 0.f);
    #pragma unroll
    for (int tc = 0; tc < 2; ++tc) {
        float gc[32];
        #pragma unroll
        for (int j = 0; j < 8; ++j) {
            float4 gv = ((const float4*)(gp + b * 64 + tc * 32))[j];
            gc[j * 4 + 0] = gv.x; gc[j * 4 + 1] = gv.y;
            gc[j * 4 + 2] = gv.z; gc[j * 4 + 3] = gv.w;
        }
        #pragma unroll
        for (int w = 0; w < 39; ++w) {                  // 32 taps + 8 rows - 1
            float4 x = *(const float4*)&S[(base + tc * 32 + w) * FC + c4 * 4];
            #pragma unroll
            for (int i = 0; i < 8; ++i) {
                int j = w - i;                          // compile-time
                if (j >= 0 && j < 32) {
                    float wt = gc[j];
                    acc[i].x += wt * x.x; acc[i].y += wt * x.y;
                    acc[i].z += wt * x.z; acc[i].w += wt * x.w;
                }
            }
        }
    }
    #pragma unroll
    for (int i = 0; i < 8; ++i) {
        size_t idx = ((size_t)b * Ln + t0 + base + i) * Dn + c0 + c4 * 4;
        ushort4 o;
        o.x = f2h(acc[i].x); o.y = f2h(acc[i].y);
        o.z = f2h(acc[i].z); o.w = f2h(acc[i].w);
        *(ushort4*)&Vf[idx] = o;
    }
}

// ---------------- f16 single-MFMA NT GEMM (m97 structure) ----------------
template <int BM, bool OUT_F16>
__global__ __launch_bounds__(256, 2) void gemm_f16(
    const unsigned short* __restrict__ A, const unsigned short* __restrict__ Bt,
    float* __restrict__ C, unsigned short* __restrict__ Cf,
    const float* __restrict__ bias,
    int N, int K, int nbx) {
    constexpr int FM = BM / 32;
    __shared__ unsigned short sA[BM * 32];
    __shared__ unsigned short sB[BM * 32];

    int nwg = gridDim.x;
    int bid = blockIdx.x;
    int swz = (bid % 8) * (nwg / 8) + bid / 8;   // nwg % 8 == 0 for our grids
    int by = swz / nbx, bx = swz % nbx;

    const int wave = threadIdx.x >> 6, lane = threadIdx.x & 63;
    const int lrow = lane & 15, lk = (lane >> 4) * 8;
    const int wr = wave >> 1, wc = wave & 1;

    f32x4 acc[FM][FM];
    #pragma unroll
    for (int i = 0; i < FM; ++i)
        #pragma unroll
        for (int j = 0; j < FM; ++j) acc[i][j] = (f32x4){0.f, 0.f, 0.f, 0.f};

    const int srow = lane >> 2;
    const int skq  = (lane & 3) * 8;

    for (int k0 = 0; k0 < K; k0 += 32) {
        #pragma unroll
        for (int j = 0; j < BM / 64; ++j) {
            int chunk = j * 4 + wave;
            int row = chunk * 16 + srow;
            gl2lds16(A  + (size_t)((by * BM) + row) * K + k0 + skq, sA + chunk * 512);
            gl2lds16(Bt + (size_t)((bx * BM) + row) * K + k0 + skq, sB + chunk * 512);
        }
        __syncthreads();
        f16x8 bfrag[FM];
        #pragma unroll
        for (int j = 0; j < FM; ++j) {
            int r = wc * (BM / 2) + j * 16 + lrow;
            bfrag[j] = *(const f16x8*)&sB[r * 32 + lk];
        }
        #pragma unroll
        for (int i = 0; i < FM; ++i) {
            int r = wr * (BM / 2) + i * 16 + lrow;
            f16x8 afrag = *(const f16x8*)&sA[r * 32 + lk];
            #pragma unroll
            for (int j = 0; j < FM; ++j)
                acc[i][j] = __builtin_amdgcn_mfma_f32_16x16x32_f16(afrag, bfrag[j], acc[i][j], 0, 0, 0);
        }
        __syncthreads();
    }
    #pragma unroll
    for (int i = 0; i < FM; ++i) {
        int r0 = by * BM + wr * (BM / 2) + i * 16 + (lane >> 4) * 4;
        #pragma unroll
        for (int j = 0; j < FM; ++j) {
            int c = bx * BM + wc * (BM / 2) + j * 16 + (lane & 15);
            float bb = OUT_F16 ? 0.f : bias[c];
            #pragma unroll
            for (int r = 0; r < 4; ++r) {
                size_t idx = (size_t)(r0 + r) * N + c;
                if (OUT_F16) Cf[idx] = f2h(acc[i][j][r]);
                else         C[idx]  = acc[i][j][r] + bb;
            }
        }
    }
}

extern "C" void kernel_launch(void* const* d_in, const int* in_sizes, int n_in,
                              void* d_out, int out_size, void* d_ws, size_t ws_size,
                              hipStream_t stream) {
    const float* q  = (const float*)d_in[0];
    const float* k  = (const float*)d_in[1];
    const float* v  = (const float*)d_in[2];
    const float* Wq = (const float*)d_in[3];
    const float* bq = (const float*)d_in[4];
    const float* Wk = (const float*)d_in[5];
    const float* bk = (const float*)d_in[6];
    const float* Wv = (const float*)d_in[7];
    const float* bv = (const float*)d_in[8];
    const float* Wo = (const float*)d_in[9];
    const float* bo = (const float*)d_in[10];
    float* out = (float*)d_out;
    float* ws  = (float*)d_ws;

    unsigned short* Vf    = (unsigned short*)ws;        // 16777216 ushort (32 MB)
    unsigned short* Wof   = Vf + 16777216;              // 1048576
    unsigned short* WvTf  = Wof + 1048576;              // 1048576
    unsigned short* Wcf   = WvTf + 1048576;             // 1048576
    float* part = (float*)(Wcf + 1048576);              // 262144 floats (1 MB)
    float* sums = part + 262144;                        // 8192
    float* SQK  = sums + 8192;                          // 8192
    float* gp   = SQK + 8192;                           // 256 (4 x 64 dense taps)
    float* bc   = gp + 256;                             // 1024
    int*   dly  = (int*)(bc + 1024);                    // 64

    // correlation-stats chain -> dense tap table gp
    hipLaunchKernelGGL(colsum_part, dim3(32, 8), dim3(256), 0, stream, q, k, part);
    hipLaunchKernelGGL(colsum_fin, dim3(4, 8), dim3(256), 0, stream, part, sums);
    hipLaunchKernelGGL(proj_sums, dim3(64, 2), dim3(256), 0, stream, sums, Wq, bq, Wk, bk, SQK);
    hipLaunchKernelGGL(stats_topk, dim3(1), dim3(256), 0, stream, SQK, dly, gp);

    // weight prep: Wo->f16, WvT->f16; Wc = Wo @ Wv (f16 out); bc = Wo@bv + bo
    hipLaunchKernelGGL(prep_w, dim3(32, 32, 2), dim3(32, 8), 0, stream, Wo, Wv, Wof, WvTf);
    hipLaunchKernelGGL((gemm_f16<64, true>), dim3(256), dim3(256), 0, stream,
                       Wof, WvTf, (float*)nullptr, Wcf, (const float*)nullptr,
                       1024, 1024, 16);
    hipLaunchKernelGGL(bcvec_k, dim3(64), dim3(256), 0, stream, Wo, bv, bo, bc);

    // gather on v as dense 64-tap FIR (2x32-tap chunks) -> f16
    hipLaunchKernelGGL(gather_fir, dim3(32, 16, 4), dim3(256), 0, stream, v, gp, Vf);

    // out = Vagg @ Wc^T + bc  (16384 x 1024 x 1024), single f16 MFMA
    hipLaunchKernelGGL((gemm_f16<128, false>), dim3(1024), dim3(256), 0, stream,
                       Vf, Wcf, out, (unsigned short*)nullptr, bc, 1024, 1024, 8);
}

// Round 11
// 135.620 us; speedup vs baseline: 1.1751x; 1.0229x over previous
//
#include <hip/hip_runtime.h>
#include <hip/hip_bf16.h>

#define Bn 4
#define Ln 4096
#define Dn 1024
#define Hn 16
#define KSEL 41
#define NT8 16   // K / 64 for the 8-phase GEMM

typedef __attribute__((ext_vector_type(8))) _Float16 f16x8;
typedef __attribute__((ext_vector_type(4))) float f32x4;

// ---------- f32 -> f16 bits (RNE via hardware cvt) ----------
__device__ __forceinline__ unsigned short f2h(float f) {
    union { _Float16 h; unsigned short u; } c;
    c.h = (_Float16)f;
    return c.u;
}

// ---------- async global->LDS, 16B per lane ----------
__device__ __forceinline__ void gl2lds16(const unsigned short* g, unsigned short* l) {
    __builtin_amdgcn_global_load_lds(
        (const __attribute__((address_space(1))) unsigned int*)(uintptr_t)g,
        (__attribute__((address_space(3))) unsigned int*)(uintptr_t)l,
        16, 0, 0);
}
__device__ __forceinline__ void gl2lds16f(const float* g, float* l) {
    __builtin_amdgcn_global_load_lds(
        (const __attribute__((address_space(1))) unsigned int*)(uintptr_t)g,
        (__attribute__((address_space(3))) unsigned int*)(uintptr_t)l,
        16, 0, 0);
}

// ---------------- column sums of q and k ----------------
// grid (64, 8): 64 rows/block -> 512 blocks = 2/CU, 8 nt-loads in flight per wave.
__global__ __launch_bounds__(256) void colsum_part(const float* __restrict__ q,
                                                   const float* __restrict__ k,
                                                   float* __restrict__ part) {
    int tb = blockIdx.y; int tensor = tb >> 2, b = tb & 3;
    const f32x4* src = (const f32x4*)((tensor ? k : q) + (size_t)b * Ln * Dn) + threadIdx.x;
    int t0 = blockIdx.x * 64;
    f32x4 a0 = (f32x4){0.f, 0.f, 0.f, 0.f};
    f32x4 a1 = (f32x4){0.f, 0.f, 0.f, 0.f};
    #pragma unroll 1
    for (int g = 0; g < 8; ++g) {
        const f32x4* p = src + (size_t)(t0 + g * 8) * 256;
        f32x4 v0 = __builtin_nontemporal_load(p + 0 * 256);
        f32x4 v1 = __builtin_nontemporal_load(p + 1 * 256);
        f32x4 v2 = __builtin_nontemporal_load(p + 2 * 256);
        f32x4 v3 = __builtin_nontemporal_load(p + 3 * 256);
        f32x4 v4 = __builtin_nontemporal_load(p + 4 * 256);
        f32x4 v5 = __builtin_nontemporal_load(p + 5 * 256);
        f32x4 v6 = __builtin_nontemporal_load(p + 6 * 256);
        f32x4 v7 = __builtin_nontemporal_load(p + 7 * 256);
        a0 += v0 + v2 + v4 + v6;
        a1 += v1 + v3 + v5 + v7;
    }
    f32x4 o = a0 + a1;
    ((f32x4*)part)[((size_t)tb * 64 + blockIdx.x) * 256 + threadIdx.x] = o;
}

// grid (4, 8): reduce 64 chunks per (tb, d)
__global__ void colsum_fin(const float* __restrict__ part, float* __restrict__ sums) {
    int tb = blockIdx.y; int d = blockIdx.x * 256 + threadIdx.x;
    float s = 0.f;
    for (int i = 0; i < 64; ++i) s += part[((size_t)tb * 64 + i) * 1024 + d];
    sums[(size_t)tb * 1024 + d] = s;
}

// ---------------- SQ/SK = colsum @ W^T + L*bias ----------------
__global__ void proj_sums(const float* __restrict__ sums,
                          const float* __restrict__ Wq, const float* __restrict__ bq,
                          const float* __restrict__ Wk, const float* __restrict__ bk,
                          float* __restrict__ SQK) {
    int t = blockIdx.y;
    const float* W    = t ? Wk : Wq;
    const float* bias = t ? bk : bq;
    const float* sv   = sums + (size_t)t * 4 * 1024;
    __shared__ float s_sv[4 * 1024];
    for (int i = threadIdx.x; i < 4 * 1024; i += 256) s_sv[i] = sv[i];
    __syncthreads();
    int wave = threadIdx.x >> 6, lane = threadIdx.x & 63;
    for (int rr = 0; rr < 4; ++rr) {
        int j = blockIdx.x * 16 + rr * 4 + wave;
        float p[4] = {0.f, 0.f, 0.f, 0.f};
        for (int c = 0; c < 4; ++c) {
            float4 wv = *(const float4*)(W + (size_t)j * 1024 + c * 256 + lane * 4);
            #pragma unroll
            for (int b = 0; b < 4; ++b) {
                float4 s = *(const float4*)(s_sv + b * 1024 + c * 256 + lane * 4);
                p[b] += wv.x * s.x + wv.y * s.y + wv.z * s.z + wv.w * s.w;
            }
        }
        #pragma unroll
        for (int b = 0; b < 4; ++b)
            for (int off = 1; off < 64; off <<= 1) p[b] += __shfl_xor(p[b], off);
        if (lane == 0) {
            float bb = bias[j] * (float)Ln;
            #pragma unroll
            for (int b = 0; b < 4; ++b) SQK[((size_t)t * 4 + b) * 1024 + j] = p[b] + bb;
        }
    }
}

// ---------------- fused mean_value + top-41 + softmax + dense tap table ----------------
__global__ void stats_topk(const float* __restrict__ SQK, int* __restrict__ dly,
                           float* __restrict__ gp) {
    __shared__ float s_mv[4][64];
    __shared__ float mab[64];
    __shared__ float selv[4][KSEL];
    __shared__ int   s_dly[KSEL];
    int tid = threadIdx.x; int b = tid >> 6, c = tid & 63;
    const float* SQ = SQK; const float* SK = SQK + 4 * 1024;
    float s = 0.f;
    for (int h = 0; h < Hn; ++h)
        s += SQ[(size_t)b * 1024 + h * 64 + c] * SK[(size_t)b * 1024 + h * 64 + c];
    s_mv[b][c] = s * (1.0f / ((float)Hn * (float)Ln));
    __syncthreads();
    if (tid < 64) mab[c] = (s_mv[0][c] + s_mv[1][c] + s_mv[2][c] + s_mv[3][c]) * 0.25f;
    __syncthreads();
    if (tid < 64) {
        float my = mab[c];
        int rank = 0;
        for (int j = 0; j < 64; ++j) {
            float vj = mab[j];
            rank += (vj > my) || (vj == my && j < c);
        }
        if (rank < KSEL) {
            s_dly[rank] = c;
            dly[rank] = c;
            selv[0][rank] = s_mv[0][c]; selv[1][rank] = s_mv[1][c];
            selv[2][rank] = s_mv[2][c]; selv[3][rank] = s_mv[3][c];
        }
    }
    __syncthreads();
    if (tid < 256) gp[tid] = 0.f;
    __syncthreads();
    if (tid < 4) {
        float mx = -1e30f;
        for (int i = 0; i < KSEL; ++i) mx = fmaxf(mx, selv[tid][i]);
        float ss = 0.f;
        for (int i = 0; i < KSEL; ++i) ss += expf(selv[tid][i] - mx);
        float inv = 1.0f / ss;
        for (int i = 0; i < KSEL; ++i)
            gp[tid * 64 + s_dly[i]] = expf(selv[tid][i] - mx) * inv;
    }
}

// ---------------- weight prep: z=0 Wo->f16 straight; z=1 Wv->transpose->f16 ----------------
__global__ void prep_w(const float* __restrict__ Wo, const float* __restrict__ Wv,
                       unsigned short* __restrict__ Wof, unsigned short* __restrict__ WvTf) {
    int bx = blockIdx.x * 32, by = blockIdx.y * 32;
    int x = threadIdx.x, y0 = threadIdx.y;
    if (blockIdx.z == 0) {
        for (int i = 0; i < 32; i += 8) {
            size_t idx = (size_t)(by + y0 + i) * 1024 + bx + x;
            Wof[idx] = f2h(Wo[idx]);
        }
    } else {
        __shared__ float t[32][33];
        for (int i = 0; i < 32; i += 8)
            t[y0 + i][x] = Wv[(size_t)(by + y0 + i) * 1024 + bx + x];
        __syncthreads();
        for (int i = 0; i < 32; i += 8)
            WvTf[(size_t)(bx + y0 + i) * 1024 + by + x] = f2h(t[x][y0 + i]);
    }
}

// ---------------- bc = Wo @ bv + bo (fp32) ----------------
__global__ void bcvec_k(const float* __restrict__ Wo, const float* __restrict__ bv,
                        const float* __restrict__ bo, float* __restrict__ bc) {
    __shared__ float s_bv[1024];
    for (int i = threadIdx.x; i < 1024; i += 256) s_bv[i] = bv[i];
    __syncthreads();
    int wave = threadIdx.x >> 6, lane = threadIdx.x & 63;
    for (int rr = 0; rr < 4; ++rr) {
        int n = blockIdx.x * 16 + rr * 4 + wave;
        float p = 0.f;
        for (int c = 0; c < 4; ++c) {
            float4 wv = *(const float4*)(Wo + (size_t)n * 1024 + c * 256 + lane * 4);
            float4 s  = *(const float4*)(s_bv + c * 256 + lane * 4);
            p += wv.x * s.x + wv.y * s.y + wv.z * s.z + wv.w * s.w;
        }
        for (int off = 1; off < 64; off <<= 1) p += __shfl_xor(p, off);
        if (lane == 0) bc[n] = p + bo[n];
    }
}

// ---------------- gather as dense 64-tap FIR, 2 chunks of 32 taps -> f16 ----------------
#define FT 128
#define FC 64
#define FW 64
__global__ __launch_bounds__(256) void gather_fir(const float* __restrict__ v,
                                                  const float* __restrict__ gp,
                                                  unsigned short* __restrict__ Vf) {
    __shared__ float S[(FT + FW) * FC];   // 192 rows x 64 ch = 48 KB
    int b = blockIdx.z, c0 = blockIdx.y * FC, t0 = blockIdx.x * FT;
    const float* Vb = v + (size_t)b * Ln * Dn;
    #pragma unroll
    for (int it = 0; it < 12; ++it) {
        int idx = it * 256 + threadIdx.x;           // 16B slot
        int r = idx >> 4, cc = idx & 15;
        int gr = (t0 + r) & (Ln - 1);
        gl2lds16f(Vb + (size_t)gr * Dn + c0 + cc * 4, S + idx * 4);
    }
    __syncthreads();
    int c4 = threadIdx.x & 15, rg = threadIdx.x >> 4;   // 16 row-groups of 8 t
    const int base = rg * 8;
    float4 acc[8];
    #pragma unroll
    for (int i = 0; i < 8; ++i) acc[i] = make_float4(0.f, 0.f, 0.f, 0.f);
    #pragma unroll
    for (int tc = 0; tc < 2; ++tc) {
        float gc[32];
        #pragma unroll
        for (int j = 0; j < 8; ++j) {
            float4 gv = ((const float4*)(gp + b * 64 + tc * 32))[j];
            gc[j * 4 + 0] = gv.x; gc[j * 4 + 1] = gv.y;
            gc[j * 4 + 2] = gv.z; gc[j * 4 + 3] = gv.w;
        }
        #pragma unroll
        for (int w = 0; w < 39; ++w) {                  // 32 taps + 8 rows - 1
            float4 x = *(const float4*)&S[(base + tc * 32 + w) * FC + c4 * 4];
            #pragma unroll
            for (int i = 0; i < 8; ++i) {
                int j = w - i;                          // compile-time
                if (j >= 0 && j < 32) {
                    float wt = gc[j];
                    acc[i].x += wt * x.x; acc[i].y += wt * x.y;
                    acc[i].z += wt * x.z; acc[i].w += wt * x.w;
                }
            }
        }
    }
    #pragma unroll
    for (int i = 0; i < 8; ++i) {
        size_t idx = ((size_t)b * Ln + t0 + base + i) * Dn + c0 + c4 * 4;
        ushort4 o;
        o.x = f2h(acc[i].x); o.y = f2h(acc[i].y);
        o.z = f2h(acc[i].z); o.w = f2h(acc[i].w);
        *(ushort4*)&Vf[idx] = o;
    }
}

// ---------------- f16 single-MFMA NT GEMM (m97 structure, small Wc GEMM) ----------------
template <int BM, bool OUT_F16>
__global__ __launch_bounds__(256, 2) void gemm_f16(
    const unsigned short* __restrict__ A, const unsigned short* __restrict__ Bt,
    float* __restrict__ C, unsigned short* __restrict__ Cf,
    const float* __restrict__ bias,
    int N, int K, int nbx) {
    constexpr int FM = BM / 32;
    __shared__ unsigned short sA[BM * 32];
    __shared__ unsigned short sB[BM * 32];

    int nwg = gridDim.x;
    int bid = blockIdx.x;
    int swz = (bid % 8) * (nwg / 8) + bid / 8;
    int by = swz / nbx, bx = swz % nbx;

    const int wave = threadIdx.x >> 6, lane = threadIdx.x & 63;
    const int lrow = lane & 15, lk = (lane >> 4) * 8;
    const int wr = wave >> 1, wc = wave & 1;

    f32x4 acc[FM][FM];
    #pragma unroll
    for (int i = 0; i < FM; ++i)
        #pragma unroll
        for (int j = 0; j < FM; ++j) acc[i][j] = (f32x4){0.f, 0.f, 0.f, 0.f};

    const int srow = lane >> 2;
    const int skq  = (lane & 3) * 8;

    for (int k0 = 0; k0 < K; k0 += 32) {
        #pragma unroll
        for (int j = 0; j < BM / 64; ++j) {
            int chunk = j * 4 + wave;
            int row = chunk * 16 + srow;
            gl2lds16(A  + (size_t)((by * BM) + row) * K + k0 + skq, sA + chunk * 512);
            gl2lds16(Bt + (size_t)((bx * BM) + row) * K + k0 + skq, sB + chunk * 512);
        }
        __syncthreads();
        f16x8 bfrag[FM];
        #pragma unroll
        for (int j = 0; j < FM; ++j) {
            int r = wc * (BM / 2) + j * 16 + lrow;
            bfrag[j] = *(const f16x8*)&sB[r * 32 + lk];
        }
        #pragma unroll
        for (int i = 0; i < FM; ++i) {
            int r = wr * (BM / 2) + i * 16 + lrow;
            f16x8 afrag = *(const f16x8*)&sA[r * 32 + lk];
            #pragma unroll
            for (int j = 0; j < FM; ++j)
                acc[i][j] = __builtin_amdgcn_mfma_f32_16x16x32_f16(afrag, bfrag[j], acc[i][j], 0, 0, 0);
        }
        __syncthreads();
    }
    #pragma unroll
    for (int i = 0; i < FM; ++i) {
        int r0 = by * BM + wr * (BM / 2) + i * 16 + (lane >> 4) * 4;
        #pragma unroll
        for (int j = 0; j < FM; ++j) {
            int c = bx * BM + wc * (BM / 2) + j * 16 + (lane & 15);
            float bb = OUT_F16 ? 0.f : bias[c];
            #pragma unroll
            for (int r = 0; r < 4; ++r) {
                size_t idx = (size_t)(r0 + r) * N + c;
                if (OUT_F16) Cf[idx] = f2h(acc[i][j][r]);
                else         C[idx]  = acc[i][j][r] + bb;
            }
        }
    }
}

// ---------------- 8-phase 256x256 f16 GEMM (T2+T3+T4+T5) ----------------
// out[m,n] = sum_k A[m,k]*Bt[n,k] + bias[n]. M=16384, N=1024, K=1024.
// 512 thr / 8 waves. Per K-tile (BK=64): 4 quadrant-phases; each phase all 8
// waves compute one 128x128 C-quadrant (16 MFMA/wave). A half-tile is ds_read
// in exactly ONE phase -> dead after; prefetch issue order p0:(t+1,B1),
// p1:(t+2,A0), p2:(t+2,B0), p3:(t+2,A1) gives steady-state vmcnt(6).
// LDS 128KB: [buf][op][half] 128x64 f16, XOR swizzle slot^=(row&7) with linear
// gl2lds dest + inverse-swizzled global source (rule #21).
__device__ __forceinline__ void mm16q(const f16x8* a, const f16x8* b, f32x4 (&acc)[2][4]) {
    #pragma unroll
    for (int i = 0; i < 2; ++i)
        #pragma unroll
        for (int j = 0; j < 4; ++j)
            #pragma unroll
            for (int s = 0; s < 2; ++s)
                acc[i][j] = __builtin_amdgcn_mfma_f32_16x16x32_f16(a[i * 2 + s], b[j * 2 + s],
                                                                   acc[i][j], 0, 0, 0);
}

__global__ __launch_bounds__(512, 2) void gemm8p(const unsigned short* __restrict__ A,
                                                 const unsigned short* __restrict__ Bt,
                                                 float* __restrict__ C,
                                                 const float* __restrict__ bias) {
    __shared__ unsigned short lds[65536];   // 128 KB
    int bid = blockIdx.x;                   // 256 blocks
    int swz = (bid & 7) * 32 + (bid >> 3);  // XCD swizzle, nwg=256 % 8 == 0
    int by = swz >> 2, bx = swz & 3;

    const int tid = threadIdx.x;
    const int wv = tid >> 6, lane = tid & 63;
    const int wr = wv >> 1, wc = wv & 1;    // wave 4x2 grid within a quadrant
    const int srow = lane >> 3, sslot = lane & 7;

    f32x4 acc[4][2][4];
    #pragma unroll
    for (int q = 0; q < 4; ++q)
        #pragma unroll
        for (int i = 0; i < 2; ++i)
            #pragma unroll
            for (int j = 0; j < 4; ++j) acc[q][i][j] = (f32x4){0.f, 0.f, 0.f, 0.f};

    // stage half (op,mh) of K-tile t into buffer t&1 (2 gl2lds per lane)
    auto STAGE = [&](int t, int op, int mh) {
        unsigned short* hb = lds + ((((t & 1) * 2 + op) * 2 + mh) << 13);
        const unsigned short* G = op ? Bt : A;
        int base_row = (op ? bx : by) * 256 + mh * 128;
        #pragma unroll
        for (int i = 0; i < 2; ++i) {
            int rl = i * 64 + wv * 8 + srow;
            int cs = sslot ^ (rl & 7);
            gl2lds16(G + (size_t)(base_row + rl) * 1024 + t * 64 + cs * 8,
                     hb + i * 4096 + wv * 512);
        }
    };
    auto LDA = [&](int t, int h, f16x8* a) {     // a[4]: i*2+s
        const unsigned short* hb = lds + ((((t & 1) * 2 + 0) * 2 + h) << 13);
        #pragma unroll
        for (int i = 0; i < 2; ++i) {
            int rl = wr * 32 + i * 16 + (lane & 15);
            #pragma unroll
            for (int s = 0; s < 2; ++s) {
                int cs = s * 4 + (lane >> 4);
                a[i * 2 + s] = *(const f16x8*)(hb + rl * 64 + ((cs ^ (rl & 7)) << 3));
            }
        }
    };
    auto LDB = [&](int t, int h, f16x8* b) {     // b[8]: j*2+s
        const unsigned short* hb = lds + ((((t & 1) * 2 + 1) * 2 + h) << 13);
        #pragma unroll
        for (int j = 0; j < 4; ++j) {
            int rl = wc * 64 + j * 16 + (lane & 15);
            #pragma unroll
            for (int s = 0; s < 2; ++s) {
                int cs = s * 4 + (lane >> 4);
                b[j * 2 + s] = *(const f16x8*)(hb + rl * 64 + ((cs ^ (rl & 7)) << 3));
            }
        }
    };

    // prologue: 7 halves (14 loads/wave); vmcnt(6) -> tile 0 landed
    STAGE(0, 0, 0); STAGE(0, 1, 0); STAGE(0, 0, 1); STAGE(0, 1, 1);
    STAGE(1, 0, 0); STAGE(1, 1, 0); STAGE(1, 0, 1);
    asm volatile("s_waitcnt vmcnt(6)" ::: "memory");
    __builtin_amdgcn_sched_barrier(0);
    __builtin_amdgcn_s_barrier();

    f16x8 a0[4], a1[4], b[8];
    for (int t = 0; t < NT8; ++t) {
        // pos0 (q=0: A-half0 x B-half0): read A-set0 + B-set0
        LDA(t, 0, a0); LDB(t, 0, b);
        asm volatile("s_waitcnt lgkmcnt(0)" ::: "memory");
        __builtin_amdgcn_sched_barrier(0);
        __builtin_amdgcn_s_barrier();
        __builtin_amdgcn_sched_barrier(0);
        if (t + 1 < NT8) STAGE(t + 1, 1, 1);           // (t+1, B1) -> other buffer
        __builtin_amdgcn_s_setprio(1);
        mm16q(a0, b, acc[0]);
        __builtin_amdgcn_s_setprio(0);
        // pos1 (q=2: A-half1 x B-half0): read A-set1, reuse B-set0
        LDA(t, 1, a1);
        asm volatile("s_waitcnt lgkmcnt(0)" ::: "memory");
        __builtin_amdgcn_sched_barrier(0);
        __builtin_amdgcn_s_barrier();
        __builtin_amdgcn_sched_barrier(0);
        if (t + 2 < NT8) STAGE(t + 2, 0, 0);           // (t+2, A0) — A0 dead since pos0
        __builtin_amdgcn_s_setprio(1);
        mm16q(a1, b, acc[2]);
        __builtin_amdgcn_s_setprio(0);
        // pos2 (q=1: A-half0 x B-half1): read B-set1, reuse A-set0
        LDB(t, 1, b);
        asm volatile("s_waitcnt lgkmcnt(0)" ::: "memory");
        __builtin_amdgcn_sched_barrier(0);
        __builtin_amdgcn_s_barrier();
        __builtin_amdgcn_sched_barrier(0);
        if (t + 2 < NT8) STAGE(t + 2, 1, 0);           // (t+2, B0) — B0 dead since pos0
        __builtin_amdgcn_s_setprio(1);
        mm16q(a0, b, acc[1]);
        __builtin_amdgcn_s_setprio(0);
        // pos3 (q=3: A-half1 x B-half1): all frags cached
        __builtin_amdgcn_s_barrier();
        __builtin_amdgcn_sched_barrier(0);
        if (t + 2 < NT8) STAGE(t + 2, 0, 1);           // (t+2, A1) — A1 dead since pos1
        __builtin_amdgcn_s_setprio(1);
        mm16q(a1, b, acc[3]);
        __builtin_amdgcn_s_setprio(0);
        // tile boundary: guarantee tile t+1 fully landed (counted wait)
        if (t + 2 < NT8) {
            asm volatile("s_waitcnt vmcnt(6)" ::: "memory");
        } else {
            asm volatile("s_waitcnt vmcnt(0)" ::: "memory");
        }
        __builtin_amdgcn_sched_barrier(0);
        __builtin_amdgcn_s_barrier();
    }

    // epilogue: C row=(lane>>4)*4+reg, col=lane&15 within each 16x16 frag
    const int lr = (lane >> 4) << 2, lc = lane & 15;
    #pragma unroll
    for (int q = 0; q < 4; ++q) {
        int rbase = by * 256 + (q >> 1) * 128 + wr * 32 + lr;
        int cbase = bx * 256 + (q & 1) * 128 + wc * 64 + lc;
        #pragma unroll
        for (int j = 0; j < 4; ++j) {
            int c = cbase + j * 16;
            float bb = bias[c];
            #pragma unroll
            for (int i = 0; i < 2; ++i)
                #pragma unroll
                for (int r = 0; r < 4; ++r)
                    C[(size_t)(rbase + i * 16 + r) * 1024 + c] = acc[q][i][j][r] + bb;
        }
    }
}

extern "C" void kernel_launch(void* const* d_in, const int* in_sizes, int n_in,
                              void* d_out, int out_size, void* d_ws, size_t ws_size,
                              hipStream_t stream) {
    const float* q  = (const float*)d_in[0];
    const float* k  = (const float*)d_in[1];
    const float* v  = (const float*)d_in[2];
    const float* Wq = (const float*)d_in[3];
    const float* bq = (const float*)d_in[4];
    const float* Wk = (const float*)d_in[5];
    const float* bk = (const float*)d_in[6];
    const float* Wv = (const float*)d_in[7];
    const float* bv = (const float*)d_in[8];
    const float* Wo = (const float*)d_in[9];
    const float* bo = (const float*)d_in[10];
    float* out = (float*)d_out;
    float* ws  = (float*)d_ws;

    unsigned short* Vf    = (unsigned short*)ws;        // 16777216 ushort (32 MB)
    unsigned short* Wof   = Vf + 16777216;              // 1048576
    unsigned short* WvTf  = Wof + 1048576;              // 1048576
    unsigned short* Wcf   = WvTf + 1048576;             // 1048576
    float* part = (float*)(Wcf + 1048576);              // 524288 floats (2 MB)
    float* sums = part + 524288;                        // 8192
    float* SQK  = sums + 8192;                          // 8192
    float* gp   = SQK + 8192;                           // 256 (4 x 64 dense taps)
    float* bc   = gp + 256;                             // 1024
    int*   dly  = (int*)(bc + 1024);                    // 64

    // correlation-stats chain -> dense tap table gp
    hipLaunchKernelGGL(colsum_part, dim3(64, 8), dim3(256), 0, stream, q, k, part);
    hipLaunchKernelGGL(colsum_fin, dim3(4, 8), dim3(256), 0, stream, part, sums);
    hipLaunchKernelGGL(proj_sums, dim3(64, 2), dim3(256), 0, stream, sums, Wq, bq, Wk, bk, SQK);
    hipLaunchKernelGGL(stats_topk, dim3(1), dim3(256), 0, stream, SQK, dly, gp);

    // weight prep: Wo->f16, WvT->f16; Wc = Wo @ Wv (f16 out); bc = Wo@bv + bo
    hipLaunchKernelGGL(prep_w, dim3(32, 32, 2), dim3(32, 8), 0, stream, Wo, Wv, Wof, WvTf);
    hipLaunchKernelGGL((gemm_f16<64, true>), dim3(256), dim3(256), 0, stream,
                       Wof, WvTf, (float*)nullptr, Wcf, (const float*)nullptr,
                       1024, 1024, 16);
    hipLaunchKernelGGL(bcvec_k, dim3(64), dim3(256), 0, stream, Wo, bv, bo, bc);

    // gather on v as dense 64-tap FIR (2x32-tap chunks) -> f16
    hipLaunchKernelGGL(gather_fir, dim3(32, 16, 4), dim3(256), 0, stream, v, gp, Vf);

    // out = Vagg @ Wc^T + bc : 8-phase 256^2 pipeline, grid 64x4 = 256 blocks
    hipLaunchKernelGGL(gemm8p, dim3(256), dim3(512), 0, stream, Vf, Wcf, out, bc);
}

// Round 12
// 135.299 us; speedup vs baseline: 1.1779x; 1.0024x over previous
//
#include <hip/hip_runtime.h>
#include <hip/hip_bf16.h>

#define Bn 4
#define Ln 4096
#define Dn 1024
#define Hn 16
#define KSEL 41
#define NT8 16   // K / 64 for the 8-phase GEMM

typedef __attribute__((ext_vector_type(8))) _Float16 f16x8;
typedef __attribute__((ext_vector_type(4))) float f32x4;

// ---------- f32 -> f16 bits (RNE via hardware cvt) ----------
__device__ __forceinline__ unsigned short f2h(float f) {
    union { _Float16 h; unsigned short u; } c;
    c.h = (_Float16)f;
    return c.u;
}

// ---------- async global->LDS, 16B per lane ----------
__device__ __forceinline__ void gl2lds16(const unsigned short* g, unsigned short* l) {
    __builtin_amdgcn_global_load_lds(
        (const __attribute__((address_space(1))) unsigned int*)(uintptr_t)g,
        (__attribute__((address_space(3))) unsigned int*)(uintptr_t)l,
        16, 0, 0);
}
__device__ __forceinline__ void gl2lds16f(const float* g, float* l) {
    __builtin_amdgcn_global_load_lds(
        (const __attribute__((address_space(1))) unsigned int*)(uintptr_t)g,
        (__attribute__((address_space(3))) unsigned int*)(uintptr_t)l,
        16, 0, 0);
}

// ---------------- column sums of q and k ----------------
// grid (64, 8): 64 rows/block -> 512 blocks = 2/CU, 8 nt-loads in flight per wave.
__global__ __launch_bounds__(256) void colsum_part(const float* __restrict__ q,
                                                   const float* __restrict__ k,
                                                   float* __restrict__ part) {
    int tb = blockIdx.y; int tensor = tb >> 2, b = tb & 3;
    const f32x4* src = (const f32x4*)((tensor ? k : q) + (size_t)b * Ln * Dn) + threadIdx.x;
    int t0 = blockIdx.x * 64;
    f32x4 a0 = (f32x4){0.f, 0.f, 0.f, 0.f};
    f32x4 a1 = (f32x4){0.f, 0.f, 0.f, 0.f};
    #pragma unroll 1
    for (int g = 0; g < 8; ++g) {
        const f32x4* p = src + (size_t)(t0 + g * 8) * 256;
        f32x4 v0 = __builtin_nontemporal_load(p + 0 * 256);
        f32x4 v1 = __builtin_nontemporal_load(p + 1 * 256);
        f32x4 v2 = __builtin_nontemporal_load(p + 2 * 256);
        f32x4 v3 = __builtin_nontemporal_load(p + 3 * 256);
        f32x4 v4 = __builtin_nontemporal_load(p + 4 * 256);
        f32x4 v5 = __builtin_nontemporal_load(p + 5 * 256);
        f32x4 v6 = __builtin_nontemporal_load(p + 6 * 256);
        f32x4 v7 = __builtin_nontemporal_load(p + 7 * 256);
        a0 += v0 + v2 + v4 + v6;
        a1 += v1 + v3 + v5 + v7;
    }
    f32x4 o = a0 + a1;
    ((f32x4*)part)[((size_t)tb * 64 + blockIdx.x) * 256 + threadIdx.x] = o;
}

// grid (4, 8): reduce 64 chunks per (tb, d)
__global__ void colsum_fin(const float* __restrict__ part, float* __restrict__ sums) {
    int tb = blockIdx.y; int d = blockIdx.x * 256 + threadIdx.x;
    float s = 0.f;
    for (int i = 0; i < 64; ++i) s += part[((size_t)tb * 64 + i) * 1024 + d];
    sums[(size_t)tb * 1024 + d] = s;
}

// ---------------- SQ/SK = colsum @ W^T + L*bias ----------------
__global__ void proj_sums(const float* __restrict__ sums,
                          const float* __restrict__ Wq, const float* __restrict__ bq,
                          const float* __restrict__ Wk, const float* __restrict__ bk,
                          float* __restrict__ SQK) {
    int t = blockIdx.y;
    const float* W    = t ? Wk : Wq;
    const float* bias = t ? bk : bq;
    const float* sv   = sums + (size_t)t * 4 * 1024;
    __shared__ float s_sv[4 * 1024];
    for (int i = threadIdx.x; i < 4 * 1024; i += 256) s_sv[i] = sv[i];
    __syncthreads();
    int wave = threadIdx.x >> 6, lane = threadIdx.x & 63;
    for (int rr = 0; rr < 4; ++rr) {
        int j = blockIdx.x * 16 + rr * 4 + wave;
        float p[4] = {0.f, 0.f, 0.f, 0.f};
        for (int c = 0; c < 4; ++c) {
            float4 wv = *(const float4*)(W + (size_t)j * 1024 + c * 256 + lane * 4);
            #pragma unroll
            for (int b = 0; b < 4; ++b) {
                float4 s = *(const float4*)(s_sv + b * 1024 + c * 256 + lane * 4);
                p[b] += wv.x * s.x + wv.y * s.y + wv.z * s.z + wv.w * s.w;
            }
        }
        #pragma unroll
        for (int b = 0; b < 4; ++b)
            for (int off = 1; off < 64; off <<= 1) p[b] += __shfl_xor(p[b], off);
        if (lane == 0) {
            float bb = bias[j] * (float)Ln;
            #pragma unroll
            for (int b = 0; b < 4; ++b) SQK[((size_t)t * 4 + b) * 1024 + j] = p[b] + bb;
        }
    }
}

// ---------------- fused mean_value + top-41 + softmax + dense tap table ----------------
__global__ void stats_topk(const float* __restrict__ SQK, int* __restrict__ dly,
                           float* __restrict__ gp) {
    __shared__ float s_mv[4][64];
    __shared__ float mab[64];
    __shared__ float selv[4][KSEL];
    __shared__ int   s_dly[KSEL];
    int tid = threadIdx.x; int b = tid >> 6, c = tid & 63;
    const float* SQ = SQK; const float* SK = SQK + 4 * 1024;
    float s = 0.f;
    for (int h = 0; h < Hn; ++h)
        s += SQ[(size_t)b * 1024 + h * 64 + c] * SK[(size_t)b * 1024 + h * 64 + c];
    s_mv[b][c] = s * (1.0f / ((float)Hn * (float)Ln));
    __syncthreads();
    if (tid < 64) mab[c] = (s_mv[0][c] + s_mv[1][c] + s_mv[2][c] + s_mv[3][c]) * 0.25f;
    __syncthreads();
    if (tid < 64) {
        float my = mab[c];
        int rank = 0;
        for (int j = 0; j < 64; ++j) {
            float vj = mab[j];
            rank += (vj > my) || (vj == my && j < c);
        }
        if (rank < KSEL) {
            s_dly[rank] = c;
            dly[rank] = c;
            selv[0][rank] = s_mv[0][c]; selv[1][rank] = s_mv[1][c];
            selv[2][rank] = s_mv[2][c]; selv[3][rank] = s_mv[3][c];
        }
    }
    __syncthreads();
    if (tid < 256) gp[tid] = 0.f;
    __syncthreads();
    if (tid < 4) {
        float mx = -1e30f;
        for (int i = 0; i < KSEL; ++i) mx = fmaxf(mx, selv[tid][i]);
        float ss = 0.f;
        for (int i = 0; i < KSEL; ++i) ss += expf(selv[tid][i] - mx);
        float inv = 1.0f / ss;
        for (int i = 0; i < KSEL; ++i)
            gp[tid * 64 + s_dly[i]] = expf(selv[tid][i] - mx) * inv;
    }
}

// ---------------- weight prep: z=0 Wo->f16 straight; z=1 Wv->transpose->f16 ----------------
__global__ void prep_w(const float* __restrict__ Wo, const float* __restrict__ Wv,
                       unsigned short* __restrict__ Wof, unsigned short* __restrict__ WvTf) {
    int bx = blockIdx.x * 32, by = blockIdx.y * 32;
    int x = threadIdx.x, y0 = threadIdx.y;
    if (blockIdx.z == 0) {
        for (int i = 0; i < 32; i += 8) {
            size_t idx = (size_t)(by + y0 + i) * 1024 + bx + x;
            Wof[idx] = f2h(Wo[idx]);
        }
    } else {
        __shared__ float t[32][33];
        for (int i = 0; i < 32; i += 8)
            t[y0 + i][x] = Wv[(size_t)(by + y0 + i) * 1024 + bx + x];
        __syncthreads();
        for (int i = 0; i < 32; i += 8)
            WvTf[(size_t)(bx + y0 + i) * 1024 + by + x] = f2h(t[x][y0 + i]);
    }
}

// ---------------- bc = Wo @ bv + bo (fp32) ----------------
__global__ void bcvec_k(const float* __restrict__ Wo, const float* __restrict__ bv,
                        const float* __restrict__ bo, float* __restrict__ bc) {
    __shared__ float s_bv[1024];
    for (int i = threadIdx.x; i < 1024; i += 256) s_bv[i] = bv[i];
    __syncthreads();
    int wave = threadIdx.x >> 6, lane = threadIdx.x & 63;
    for (int rr = 0; rr < 4; ++rr) {
        int n = blockIdx.x * 16 + rr * 4 + wave;
        float p = 0.f;
        for (int c = 0; c < 4; ++c) {
            float4 wv = *(const float4*)(Wo + (size_t)n * 1024 + c * 256 + lane * 4);
            float4 s  = *(const float4*)(s_bv + c * 256 + lane * 4);
            p += wv.x * s.x + wv.y * s.y + wv.z * s.z + wv.w * s.w;
        }
        for (int off = 1; off < 64; off <<= 1) p += __shfl_xor(p, off);
        if (lane == 0) bc[n] = p + bo[n];
    }
}

// ---------------- gather as dense 64-tap FIR, 2 chunks of 32 taps -> f16 ----------------
#define FT 128
#define FC 64
#define FW 64
__global__ __launch_bounds__(256) void gather_fir(const float* __restrict__ v,
                                                  const float* __restrict__ gp,
                                                  unsigned short* __restrict__ Vf) {
    __shared__ float S[(FT + FW) * FC];   // 192 rows x 64 ch = 48 KB
    int b = blockIdx.z, c0 = blockIdx.y * FC, t0 = blockIdx.x * FT;
    const float* Vb = v + (size_t)b * Ln * Dn;
    #pragma unroll
    for (int it = 0; it < 12; ++it) {
        int idx = it * 256 + threadIdx.x;           // 16B slot
        int r = idx >> 4, cc = idx & 15;
        int gr = (t0 + r) & (Ln - 1);
        gl2lds16f(Vb + (size_t)gr * Dn + c0 + cc * 4, S + idx * 4);
    }
    __syncthreads();
    int c4 = threadIdx.x & 15, rg = threadIdx.x >> 4;   // 16 row-groups of 8 t
    const int base = rg * 8;
    float4 acc[8];
    #pragma unroll
    for (int i = 0; i < 8; ++i) acc[i] = make_float4(0.f, 0.f, 0.f, 0.f);
    #pragma unroll
    for (int tc = 0; tc < 2; ++tc) {
        float gc[32];
        #pragma unroll
        for (int j = 0; j < 8; ++j) {
            float4 gv = ((const float4*)(gp + b * 64 + tc * 32))[j];
            gc[j * 4 + 0] = gv.x; gc[j * 4 + 1] = gv.y;
            gc[j * 4 + 2] = gv.z; gc[j * 4 + 3] = gv.w;
        }
        #pragma unroll
        for (int w = 0; w < 39; ++w) {                  // 32 taps + 8 rows - 1
            float4 x = *(const float4*)&S[(base + tc * 32 + w) * FC + c4 * 4];
            #pragma unroll
            for (int i = 0; i < 8; ++i) {
                int j = w - i;                          // compile-time
                if (j >= 0 && j < 32) {
                    float wt = gc[j];
                    acc[i].x += wt * x.x; acc[i].y += wt * x.y;
                    acc[i].z += wt * x.z; acc[i].w += wt * x.w;
                }
            }
        }
    }
    #pragma unroll
    for (int i = 0; i < 8; ++i) {
        size_t idx = ((size_t)b * Ln + t0 + base + i) * Dn + c0 + c4 * 4;
        ushort4 o;
        o.x = f2h(acc[i].x); o.y = f2h(acc[i].y);
        o.z = f2h(acc[i].z); o.w = f2h(acc[i].w);
        *(ushort4*)&Vf[idx] = o;
    }
}

// ---------------- f16 single-MFMA NT GEMM (m97 structure, small Wc GEMM) ----------------
template <int BM, bool OUT_F16>
__global__ __launch_bounds__(256, 2) void gemm_f16(
    const unsigned short* __restrict__ A, const unsigned short* __restrict__ Bt,
    float* __restrict__ C, unsigned short* __restrict__ Cf,
    const float* __restrict__ bias,
    int N, int K, int nbx) {
    constexpr int FM = BM / 32;
    __shared__ unsigned short sA[BM * 32];
    __shared__ unsigned short sB[BM * 32];

    int nwg = gridDim.x;
    int bid = blockIdx.x;
    int swz = (bid % 8) * (nwg / 8) + bid / 8;
    int by = swz / nbx, bx = swz % nbx;

    const int wave = threadIdx.x >> 6, lane = threadIdx.x & 63;
    const int lrow = lane & 15, lk = (lane >> 4) * 8;
    const int wr = wave >> 1, wc = wave & 1;

    f32x4 acc[FM][FM];
    #pragma unroll
    for (int i = 0; i < FM; ++i)
        #pragma unroll
        for (int j = 0; j < FM; ++j) acc[i][j] = (f32x4){0.f, 0.f, 0.f, 0.f};

    const int srow = lane >> 2;
    const int skq  = (lane & 3) * 8;

    for (int k0 = 0; k0 < K; k0 += 32) {
        #pragma unroll
        for (int j = 0; j < BM / 64; ++j) {
            int chunk = j * 4 + wave;
            int row = chunk * 16 + srow;
            gl2lds16(A  + (size_t)((by * BM) + row) * K + k0 + skq, sA + chunk * 512);
            gl2lds16(Bt + (size_t)((bx * BM) + row) * K + k0 + skq, sB + chunk * 512);
        }
        __syncthreads();
        f16x8 bfrag[FM];
        #pragma unroll
        for (int j = 0; j < FM; ++j) {
            int r = wc * (BM / 2) + j * 16 + lrow;
            bfrag[j] = *(const f16x8*)&sB[r * 32 + lk];
        }
        #pragma unroll
        for (int i = 0; i < FM; ++i) {
            int r = wr * (BM / 2) + i * 16 + lrow;
            f16x8 afrag = *(const f16x8*)&sA[r * 32 + lk];
            #pragma unroll
            for (int j = 0; j < FM; ++j)
                acc[i][j] = __builtin_amdgcn_mfma_f32_16x16x32_f16(afrag, bfrag[j], acc[i][j], 0, 0, 0);
        }
        __syncthreads();
    }
    #pragma unroll
    for (int i = 0; i < FM; ++i) {
        int r0 = by * BM + wr * (BM / 2) + i * 16 + (lane >> 4) * 4;
        #pragma unroll
        for (int j = 0; j < FM; ++j) {
            int c = bx * BM + wc * (BM / 2) + j * 16 + (lane & 15);
            float bb = OUT_F16 ? 0.f : bias[c];
            #pragma unroll
            for (int r = 0; r < 4; ++r) {
                size_t idx = (size_t)(r0 + r) * N + c;
                if (OUT_F16) Cf[idx] = f2h(acc[i][j][r]);
                else         C[idx]  = acc[i][j][r] + bb;
            }
        }
    }
}

// ---------------- 8-phase 256x256 f16 GEMM, template-exact phase order ----------------
// Per phase: {ds_read frags; STAGE prefetch; s_barrier; lgkmcnt(0); sched_barrier;
// setprio(1); 16 MFMA; setprio(0); s_barrier}. Counted vmcnt(6) once per tile
// (vmcnt(0) for the last two tiles — required for the tail, see deadness audit).
// Round-11 lesson: lgkmcnt BEFORE the barrier + triple sched_barrier(0) per phase
// serialized the pipe (m141-style order-pinning) -> 45us. This matches m201.
__device__ __forceinline__ void mm16q(const f16x8* a, const f16x8* b, f32x4 (&acc)[2][4]) {
    #pragma unroll
    for (int i = 0; i < 2; ++i)
        #pragma unroll
        for (int j = 0; j < 4; ++j)
            #pragma unroll
            for (int s = 0; s < 2; ++s)
                acc[i][j] = __builtin_amdgcn_mfma_f32_16x16x32_f16(a[i * 2 + s], b[j * 2 + s],
                                                                   acc[i][j], 0, 0, 0);
}

__global__ __launch_bounds__(512, 2) void gemm8p(const unsigned short* __restrict__ A,
                                                 const unsigned short* __restrict__ Bt,
                                                 float* __restrict__ C,
                                                 const float* __restrict__ bias) {
    __shared__ unsigned short lds[65536];   // 128 KB
    int bid = blockIdx.x;                   // 256 blocks
    int swz = (bid & 7) * 32 + (bid >> 3);  // XCD swizzle, nwg=256 % 8 == 0
    int by = swz >> 2, bx = swz & 3;

    const int tid = threadIdx.x;
    const int wv = tid >> 6, lane = tid & 63;
    const int wr = wv >> 1, wc = wv & 1;    // wave 4x2 grid within a quadrant
    const int srow = lane >> 3, sslot = lane & 7;

    f32x4 acc[4][2][4];
    #pragma unroll
    for (int q = 0; q < 4; ++q)
        #pragma unroll
        for (int i = 0; i < 2; ++i)
            #pragma unroll
            for (int j = 0; j < 4; ++j) acc[q][i][j] = (f32x4){0.f, 0.f, 0.f, 0.f};

    // stage half (op,mh) of K-tile t into buffer t&1 (2 gl2lds per lane)
    auto STAGE = [&](int t, int op, int mh) {
        unsigned short* hb = lds + ((((t & 1) * 2 + op) * 2 + mh) << 13);
        const unsigned short* G = op ? Bt : A;
        int base_row = (op ? bx : by) * 256 + mh * 128;
        #pragma unroll
        for (int i = 0; i < 2; ++i) {
            int rl = i * 64 + wv * 8 + srow;
            int cs = sslot ^ (rl & 7);
            gl2lds16(G + (size_t)(base_row + rl) * 1024 + t * 64 + cs * 8,
                     hb + i * 4096 + wv * 512);
        }
    };
    auto LDA = [&](int t, int h, f16x8* a) {     // a[4]: i*2+s
        const unsigned short* hb = lds + ((((t & 1) * 2 + 0) * 2 + h) << 13);
        #pragma unroll
        for (int i = 0; i < 2; ++i) {
            int rl = wr * 32 + i * 16 + (lane & 15);
            #pragma unroll
            for (int s = 0; s < 2; ++s) {
                int cs = s * 4 + (lane >> 4);
                a[i * 2 + s] = *(const f16x8*)(hb + rl * 64 + ((cs ^ (rl & 7)) << 3));
            }
        }
    };
    auto LDB = [&](int t, int h, f16x8* b) {     // b[8]: j*2+s
        const unsigned short* hb = lds + ((((t & 1) * 2 + 1) * 2 + h) << 13);
        #pragma unroll
        for (int j = 0; j < 4; ++j) {
            int rl = wc * 64 + j * 16 + (lane & 15);
            #pragma unroll
            for (int s = 0; s < 2; ++s) {
                int cs = s * 4 + (lane >> 4);
                b[j * 2 + s] = *(const f16x8*)(hb + rl * 64 + ((cs ^ (rl & 7)) << 3));
            }
        }
    };

    // prologue: 7 halves (14 loads/lane); vmcnt(6) -> tile 0 landed
    STAGE(0, 0, 0); STAGE(0, 1, 0); STAGE(0, 0, 1); STAGE(0, 1, 1);
    STAGE(1, 0, 0); STAGE(1, 1, 0); STAGE(1, 0, 1);
    asm volatile("s_waitcnt vmcnt(6)" ::: "memory");
    __builtin_amdgcn_s_barrier();

    f16x8 a0[4], a1[4], b[8];
    for (int t = 0; t < NT8; ++t) {
        const bool p1 = (t + 1 < NT8), p2 = (t + 2 < NT8);
        // pos0 (q=0: A0 x B0)
        LDA(t, 0, a0); LDB(t, 0, b);
        if (p1) STAGE(t + 1, 1, 1);
        __builtin_amdgcn_s_barrier();
        asm volatile("s_waitcnt lgkmcnt(0)" ::: "memory");
        __builtin_amdgcn_sched_barrier(0);
        __builtin_amdgcn_s_setprio(1);
        mm16q(a0, b, acc[0]);
        __builtin_amdgcn_s_setprio(0);
        __builtin_amdgcn_s_barrier();
        // pos1 (q=2: A1 x B0)
        LDA(t, 1, a1);
        if (p2) STAGE(t + 2, 0, 0);           // A0 dead since pos0 (all waves past lgkmcnt)
        __builtin_amdgcn_s_barrier();
        asm volatile("s_waitcnt lgkmcnt(0)" ::: "memory");
        __builtin_amdgcn_sched_barrier(0);
        __builtin_amdgcn_s_setprio(1);
        mm16q(a1, b, acc[2]);
        __builtin_amdgcn_s_setprio(0);
        __builtin_amdgcn_s_barrier();
        // pos2 (q=1: A0 x B1)
        LDB(t, 1, b);
        if (p2) STAGE(t + 2, 1, 0);           // B0 dead since pos1
        __builtin_amdgcn_s_barrier();
        asm volatile("s_waitcnt lgkmcnt(0)" ::: "memory");
        __builtin_amdgcn_sched_barrier(0);
        __builtin_amdgcn_s_setprio(1);
        mm16q(a0, b, acc[1]);
        __builtin_amdgcn_s_setprio(0);
        __builtin_amdgcn_s_barrier();
        // pos3 (q=3: A1 x B1, frags cached)
        if (p2) STAGE(t + 2, 0, 1);           // A1 dead since pos1
        if (p2) { asm volatile("s_waitcnt vmcnt(6)" ::: "memory"); }
        else    { asm volatile("s_waitcnt vmcnt(0)" ::: "memory"); }
        __builtin_amdgcn_s_barrier();
        __builtin_amdgcn_s_setprio(1);
        mm16q(a1, b, acc[3]);
        __builtin_amdgcn_s_setprio(0);
        __builtin_amdgcn_s_barrier();
    }

    // epilogue: C row=(lane>>4)*4+reg, col=lane&15 within each 16x16 frag
    const int lr = (lane >> 4) << 2, lc = lane & 15;
    #pragma unroll
    for (int q = 0; q < 4; ++q) {
        int rbase = by * 256 + (q >> 1) * 128 + wr * 32 + lr;
        int cbase = bx * 256 + (q & 1) * 128 + wc * 64 + lc;
        #pragma unroll
        for (int j = 0; j < 4; ++j) {
            int c = cbase + j * 16;
            float bb = bias[c];
            #pragma unroll
            for (int i = 0; i < 2; ++i)
                #pragma unroll
                for (int r = 0; r < 4; ++r)
                    C[(size_t)(rbase + i * 16 + r) * 1024 + c] = acc[q][i][j][r] + bb;
        }
    }
}

extern "C" void kernel_launch(void* const* d_in, const int* in_sizes, int n_in,
                              void* d_out, int out_size, void* d_ws, size_t ws_size,
                              hipStream_t stream) {
    const float* q  = (const float*)d_in[0];
    const float* k  = (const float*)d_in[1];
    const float* v  = (const float*)d_in[2];
    const float* Wq = (const float*)d_in[3];
    const float* bq = (const float*)d_in[4];
    const float* Wk = (const float*)d_in[5];
    const float* bk = (const float*)d_in[6];
    const float* Wv = (const float*)d_in[7];
    const float* bv = (const float*)d_in[8];
    const float* Wo = (const float*)d_in[9];
    const float* bo = (const float*)d_in[10];
    float* out = (float*)d_out;
    float* ws  = (float*)d_ws;

    unsigned short* Vf    = (unsigned short*)ws;        // 16777216 ushort (32 MB)
    unsigned short* Wof   = Vf + 16777216;              // 1048576
    unsigned short* WvTf  = Wof + 1048576;              // 1048576
    unsigned short* Wcf   = WvTf + 1048576;             // 1048576
    float* part = (float*)(Wcf + 1048576);              // 524288 floats (2 MB)
    float* sums = part + 524288;                        // 8192
    float* SQK  = sums + 8192;                          // 8192
    float* gp   = SQK + 8192;                           // 256 (4 x 64 dense taps)
    float* bc   = gp + 256;                             // 1024
    int*   dly  = (int*)(bc + 1024);                    // 64

    // correlation-stats chain -> dense tap table gp
    hipLaunchKernelGGL(colsum_part, dim3(64, 8), dim3(256), 0, stream, q, k, part);
    hipLaunchKernelGGL(colsum_fin, dim3(4, 8), dim3(256), 0, stream, part, sums);
    hipLaunchKernelGGL(proj_sums, dim3(64, 2), dim3(256), 0, stream, sums, Wq, bq, Wk, bk, SQK);
    hipLaunchKernelGGL(stats_topk, dim3(1), dim3(256), 0, stream, SQK, dly, gp);

    // weight prep: Wo->f16, WvT->f16; Wc = Wo @ Wv (f16 out); bc = Wo@bv + bo
    hipLaunchKernelGGL(prep_w, dim3(32, 32, 2), dim3(32, 8), 0, stream, Wo, Wv, Wof, WvTf);
    hipLaunchKernelGGL((gemm_f16<64, true>), dim3(256), dim3(256), 0, stream,
                       Wof, WvTf, (float*)nullptr, Wcf, (const float*)nullptr,
                       1024, 1024, 16);
    hipLaunchKernelGGL(bcvec_k, dim3(64), dim3(256), 0, stream, Wo, bv, bo, bc);

    // gather on v as dense 64-tap FIR (2x32-tap chunks) -> f16
    hipLaunchKernelGGL(gather_fir, dim3(32, 16, 4), dim3(256), 0, stream, v, gp, Vf);

    // out = Vagg @ Wc^T + bc : 8-phase 256^2 pipeline, grid 64x4 = 256 blocks
    hipLaunchKernelGGL(gemm8p, dim3(256), dim3(512), 0, stream, Vf, Wcf, out, bc);
}